// Round 1
// baseline (465.539 us; speedup 1.0000x reference)
//
#include <hip/hip_runtime.h>

#define NN 50000
#define NE 800000
#define FIN 512
#define HID 128
#define NOUT 40

typedef __bf16 v8bf __attribute__((ext_vector_type(8)));
typedef float  v4f  __attribute__((ext_vector_type(4)));
typedef unsigned short us8 __attribute__((ext_vector_type(8)));
typedef unsigned short us4 __attribute__((ext_vector_type(4)));

static __device__ __forceinline__ unsigned short f2bf(float f) {
  union { float f; unsigned int u; } v; v.f = f;
  unsigned int r = v.u + 0x7FFFu + ((v.u >> 16) & 1u);
  return (unsigned short)(r >> 16);
}

// ---------- W1 [FIN][HID] f32 -> W1t [HID][FIN] bf16 ----------
__global__ void k_w1t(const float* __restrict__ W1, unsigned short* __restrict__ W1t) {
  int id = blockIdx.x * 256 + threadIdx.x;   // FIN*HID = 65536 threads
  int k = id >> 7;        // 0..511
  int n = id & 127;       // 0..127
  W1t[n * FIN + k] = f2bf(W1[k * HID + n]);
}

// ---------- GEMM1: h0[NN][HID] = x @ W1  (bf16 MFMA, fp32 acc) ----------
#define BM1 64
#define BK1 64
#define BKP1 72   // padded LDS row stride (elements); 144B rows keep 16B align
__global__ __launch_bounds__(256) void k_gemm1(const float* __restrict__ x,
                                               const unsigned short* __restrict__ W1t,
                                               float* __restrict__ h0) {
  __shared__ unsigned short As[BM1 * BKP1];   // 9216 B
  __shared__ unsigned short Bs[HID * BKP1];   // 18432 B
  const int t = threadIdx.x;
  const int r0 = blockIdx.x * BM1;
  const int wave = t >> 6, lane = t & 63;
  const int quad = lane >> 4, mr = lane & 15;
  const int mrow0 = (wave & 1) * 32;     // wave's 32-row half
  const int ncol0 = (wave >> 1) * 64;    // wave's 64-col half

  // A staging map: 4 threads per row, 64B contiguous per 4-lane group
  const int ar = t >> 2, aq = t & 3;
  int grow = r0 + ar; if (grow > NN - 1) grow = NN - 1;
  const float4* xrow = (const float4*)(x + (size_t)grow * FIN);
  // B staging map: 2 threads per n-row of W1t
  const int bn = t >> 1, bh = t & 1;

  const v4f vzero = {0.f, 0.f, 0.f, 0.f};
  v4f acc[2][4];
  #pragma unroll
  for (int mi = 0; mi < 2; ++mi)
    #pragma unroll
    for (int j = 0; j < 4; ++j) acc[mi][j] = vzero;

  for (int k0 = 0; k0 < FIN; k0 += BK1) {
    float4 va[4];
    #pragma unroll
    for (int i = 0; i < 4; ++i) va[i] = xrow[(k0 >> 2) + aq + i * 4];
    us8 vb[4];
    const us8* bp = (const us8*)(W1t + bn * FIN + k0 + bh * 32);
    #pragma unroll
    for (int i = 0; i < 4; ++i) vb[i] = bp[i];

    __syncthreads();   // protect previous iter's LDS reads
    #pragma unroll
    for (int i = 0; i < 4; ++i) {
      us4 s; s.x = f2bf(va[i].x); s.y = f2bf(va[i].y);
             s.z = f2bf(va[i].z); s.w = f2bf(va[i].w);
      *(us4*)&As[ar * BKP1 + aq * 4 + i * 16] = s;
    }
    #pragma unroll
    for (int i = 0; i < 4; ++i)
      *(us8*)&Bs[bn * BKP1 + bh * 32 + i * 8] = vb[i];
    __syncthreads();

    #pragma unroll
    for (int ks = 0; ks < BK1; ks += 32) {
      v8bf a0 = *(const v8bf*)&As[(mrow0 + mr) * BKP1 + ks + quad * 8];
      v8bf a1 = *(const v8bf*)&As[(mrow0 + 16 + mr) * BKP1 + ks + quad * 8];
      #pragma unroll
      for (int j = 0; j < 4; ++j) {
        v8bf b = *(const v8bf*)&Bs[(ncol0 + j * 16 + mr) * BKP1 + ks + quad * 8];
        acc[0][j] = __builtin_amdgcn_mfma_f32_16x16x32_bf16(a0, b, acc[0][j], 0, 0, 0);
        acc[1][j] = __builtin_amdgcn_mfma_f32_16x16x32_bf16(a1, b, acc[1][j], 0, 0, 0);
      }
    }
  }

  #pragma unroll
  for (int mi = 0; mi < 2; ++mi)
    #pragma unroll
    for (int j = 0; j < 4; ++j)
      #pragma unroll
      for (int rr = 0; rr < 4; ++rr) {
        int row = r0 + mrow0 + mi * 16 + quad * 4 + rr;   // C/D: row=(lane>>4)*4+reg
        int col = ncol0 + j * 16 + mr;                    //      col=lane&15
        if (row < NN) h0[(size_t)row * HID + col] = acc[mi][j][rr];
      }
}

// ---------- CSR build (rebuilt every call; ws is re-poisoned) ----------
__global__ void k_count(const int* __restrict__ dst, int* __restrict__ counts) {
  int e = blockIdx.x * 256 + threadIdx.x;
  if (e < NE) atomicAdd(&counts[dst[e]], 1);
}

__global__ __launch_bounds__(1024) void k_scan(const int* __restrict__ counts,
                                               int* __restrict__ rowptr,
                                               int* __restrict__ nxt) {
  __shared__ int wsum[16];
  __shared__ int carry_s;
  const int t = threadIdx.x, lane = t & 63, wid = t >> 6;
  if (t == 0) carry_s = 0;
  __syncthreads();
  for (int base = 0; base < NN; base += 1024) {
    int idx = base + t;
    int v = (idx < NN) ? counts[idx] : 0;
    int s = v;
    #pragma unroll
    for (int off = 1; off < 64; off <<= 1) {
      int u = __shfl_up(s, off);
      if (lane >= off) s += u;
    }
    if (lane == 63) wsum[wid] = s;
    __syncthreads();
    if (wid == 0) {
      int ws = (lane < 16) ? wsum[lane] : 0;
      #pragma unroll
      for (int off = 1; off < 16; off <<= 1) {
        int u = __shfl_up(ws, off);
        if (lane >= off) ws += u;
      }
      if (lane < 16) wsum[lane] = ws;
    }
    __syncthreads();
    int woff = (wid > 0) ? wsum[wid - 1] : 0;
    int incl = s + woff;
    int carry = carry_s;
    if (idx < NN) { int val = carry + incl - v; rowptr[idx] = val; nxt[idx] = val; }
    __syncthreads();
    if (t == 1023) carry_s = carry + incl;
    __syncthreads();
  }
  if (t == 0) rowptr[NN] = carry_s;
}

__global__ void k_scatter(const int* __restrict__ src, const int* __restrict__ dst,
                          const float* __restrict__ w, int* __restrict__ nxt,
                          int* __restrict__ csr_src, float* __restrict__ csr_w) {
  int e = blockIdx.x * 256 + threadIdx.x;
  if (e < NE) {
    int i = dst[e];
    int p = atomicAdd(&nxt[i], 1);
    csr_src[p] = src[e];
    csr_w[p]   = w[e];
  }
}

// ---------- SpMM1 (gather) + bias + relu + dropout, output bf16 ----------
__global__ __launch_bounds__(256) void k_spmm1(const float* __restrict__ h0,
                                               const int* __restrict__ rowptr,
                                               const int* __restrict__ csr_src,
                                               const float* __restrict__ csr_w,
                                               const float* __restrict__ b1,
                                               const float* __restrict__ mask,
                                               unsigned short* __restrict__ h_bf) {
  const int t = threadIdx.x;
  const int col = t & 127;
  const int i = blockIdx.x * 2 + (t >> 7);   // 2 rows/block, uniform per 2-wave group
  const int e0 = rowptr[i], e1 = rowptr[i + 1];
  float a0 = 0.f, a1 = 0.f, a2 = 0.f, a3 = 0.f;
  int e = e0;
  for (; e + 3 < e1; e += 4) {   // unroll-4: keep 4 gathers in flight
    int s0 = csr_src[e], s1 = csr_src[e+1], s2 = csr_src[e+2], s3 = csr_src[e+3];
    float w0 = csr_w[e], w1 = csr_w[e+1], w2 = csr_w[e+2], w3 = csr_w[e+3];
    a0 += w0 * h0[s0 * HID + col];
    a1 += w1 * h0[s1 * HID + col];
    a2 += w2 * h0[s2 * HID + col];
    a3 += w3 * h0[s3 * HID + col];
  }
  for (; e < e1; ++e) a0 += csr_w[e] * h0[csr_src[e] * HID + col];
  float v = (a0 + a1) + (a2 + a3) + b1[col];
  v = fmaxf(v, 0.f) * mask[i * HID + col];
  h_bf[i * HID + col] = f2bf(v);
}

// ---------- GEMM2: h2[NN][40] = h @ W2 (bf16 MFMA, 48-col padded) ----------
#define BKP2 136
__global__ __launch_bounds__(256) void k_gemm2(const unsigned short* __restrict__ h_bf,
                                               const float* __restrict__ W2,
                                               float* __restrict__ h2) {
  __shared__ unsigned short As[64 * BKP2];   // 17408 B
  __shared__ unsigned short Bs[48 * BKP2];   // 13056 B
  const int t = threadIdx.x;
  const int r0 = blockIdx.x * 64;
  const int wave = t >> 6, lane = t & 63;
  const int quad = lane >> 4, mr = lane & 15;
  const int mrow0 = wave * 16;

  // A staging: bf16 rows, 4 threads/row, 16B vector copies
  const int ar = t >> 2, aq = t & 3;
  int grow = r0 + ar; if (grow > NN - 1) grow = NN - 1;
  const us8* hrow = (const us8*)(h_bf + grow * HID);
  #pragma unroll
  for (int i = 0; i < 4; ++i) {
    us8 v = hrow[aq + i * 4];
    *(us8*)&As[ar * BKP2 + aq * 8 + i * 32] = v;
  }
  // B staging: Bs[n][k] = bf16(W2[k][n]); n in [40,48) zero-padded
  if (t < 192) {
    int n = t >> 2, q = t & 3;
    #pragma unroll
    for (int kk = 0; kk < 32; ++kk) {
      int k = q * 32 + kk;
      float val = (n < NOUT) ? W2[k * NOUT + n] : 0.f;
      Bs[n * BKP2 + k] = f2bf(val);
    }
  }
  __syncthreads();

  const v4f vzero = {0.f, 0.f, 0.f, 0.f};
  v4f acc[3] = {vzero, vzero, vzero};
  #pragma unroll
  for (int ks = 0; ks < HID; ks += 32) {
    v8bf a = *(const v8bf*)&As[(mrow0 + mr) * BKP2 + ks + quad * 8];
    #pragma unroll
    for (int j = 0; j < 3; ++j) {
      v8bf b = *(const v8bf*)&Bs[(j * 16 + mr) * BKP2 + ks + quad * 8];
      acc[j] = __builtin_amdgcn_mfma_f32_16x16x32_bf16(a, b, acc[j], 0, 0, 0);
    }
  }
  #pragma unroll
  for (int j = 0; j < 3; ++j)
    #pragma unroll
    for (int rr = 0; rr < 4; ++rr) {
      int row = r0 + mrow0 + quad * 4 + rr;
      int col = j * 16 + mr;
      if (row < NN && col < NOUT) h2[row * NOUT + col] = acc[j][rr];
    }
}

// ---------- SpMM2 (gather) + b2 -> out ----------
__global__ __launch_bounds__(256) void k_spmm2(const float* __restrict__ h2,
                                               const int* __restrict__ rowptr,
                                               const int* __restrict__ csr_src,
                                               const float* __restrict__ csr_w,
                                               const float* __restrict__ b2,
                                               float* __restrict__ out) {
  const int t = threadIdx.x;
  const int lane = t & 63;
  const int i = blockIdx.x * 4 + (t >> 6);   // one wave per row
  if (i >= NN) return;
  const int e0 = rowptr[i], e1 = rowptr[i + 1];
  if (lane >= NOUT) return;   // uniform predication within wave
  float a0 = 0.f, a1 = 0.f, a2 = 0.f, a3 = 0.f;
  int e = e0;
  for (; e + 3 < e1; e += 4) {
    int s0 = csr_src[e], s1 = csr_src[e+1], s2 = csr_src[e+2], s3 = csr_src[e+3];
    float w0 = csr_w[e], w1 = csr_w[e+1], w2 = csr_w[e+2], w3 = csr_w[e+3];
    a0 += w0 * h2[s0 * NOUT + lane];
    a1 += w1 * h2[s1 * NOUT + lane];
    a2 += w2 * h2[s2 * NOUT + lane];
    a3 += w3 * h2[s3 * NOUT + lane];
  }
  for (; e < e1; ++e) a0 += csr_w[e] * h2[csr_src[e] * NOUT + lane];
  out[i * NOUT + lane] = (a0 + a1) + (a2 + a3) + b2[lane];
}

extern "C" void kernel_launch(void* const* d_in, const int* in_sizes, int n_in,
                              void* d_out, int out_size, void* d_ws, size_t ws_size,
                              hipStream_t stream) {
  const float* x   = (const float*)d_in[0];
  const float* W1  = (const float*)d_in[1];
  const float* b1  = (const float*)d_in[2];
  const float* W2  = (const float*)d_in[3];
  const float* b2  = (const float*)d_in[4];
  const float* ew  = (const float*)d_in[5];
  const float* msk = (const float*)d_in[6];
  const int* esrc  = (const int*)d_in[7];
  const int* edst  = (const int*)d_in[8];
  float* out = (float*)d_out;

  char* ws = (char*)d_ws;
  float* h0            = (float*)ws;          ws += (size_t)NN * HID * 4;   // 25.6 MB
  unsigned short* h_bf = (unsigned short*)ws; ws += (size_t)NN * HID * 2;   // 12.8 MB
  float* h2            = (float*)ws;          ws += (size_t)NN * NOUT * 4;  // 8 MB
  unsigned short* W1t  = (unsigned short*)ws; ws += (size_t)HID * FIN * 2;  // 128 KB
  int* counts          = (int*)ws;            ws += (size_t)NN * 4;
  int* rowptr          = (int*)ws;            ws += (size_t)(NN + 4) * 4;
  int* nxt             = (int*)ws;            ws += (size_t)NN * 4;
  int* csr_src         = (int*)ws;            ws += (size_t)NE * 4;
  float* csr_w         = (float*)ws;          ws += (size_t)NE * 4;
  // total ~53.5 MB of ws

  hipMemsetAsync(counts, 0, (size_t)NN * 4, stream);
  k_w1t    <<<(FIN * HID) / 256, 256, 0, stream>>>(W1, W1t);
  k_gemm1  <<<(NN + BM1 - 1) / BM1, 256, 0, stream>>>(x, W1t, h0);
  k_count  <<<(NE + 255) / 256, 256, 0, stream>>>(edst, counts);
  k_scan   <<<1, 1024, 0, stream>>>(counts, rowptr, nxt);
  k_scatter<<<(NE + 255) / 256, 256, 0, stream>>>(esrc, edst, ew, nxt, csr_src, csr_w);
  k_spmm1  <<<NN / 2, 256, 0, stream>>>(h0, rowptr, csr_src, csr_w, b1, msk, h_bf);
  k_gemm2  <<<(NN + 63) / 64, 256, 0, stream>>>(h_bf, W2, h2);
  k_spmm2  <<<(NN + 3) / 4, 256, 0, stream>>>(h2, rowptr, csr_src, csr_w, b2, out);
}

// Round 2
// 386.597 us; speedup vs baseline: 1.2042x; 1.2042x over previous
//
#include <hip/hip_runtime.h>

#define NN 50000
#define NE 800000
#define FIN 512
#define HID 128
#define NOUT 40
#define NB_SCAN 49   // ceil(50000/1024)

typedef __bf16 v8bf __attribute__((ext_vector_type(8)));
typedef float  v4f  __attribute__((ext_vector_type(4)));
typedef unsigned short us8 __attribute__((ext_vector_type(8)));
typedef unsigned short us4 __attribute__((ext_vector_type(4)));

static __device__ __forceinline__ unsigned short f2bf(float f) {
  union { float f; unsigned int u; } v; v.f = f;
  unsigned int r = v.u + 0x7FFFu + ((v.u >> 16) & 1u);
  return (unsigned short)(r >> 16);
}
static __device__ __forceinline__ float bf2f(unsigned short s) {
  union { unsigned int u; float f; } v; v.u = ((unsigned int)s) << 16;
  return v.f;
}
static __device__ __forceinline__ float bf_lo(unsigned int u) {
  union { unsigned int u; float f; } v; v.u = u << 16; return v.f;
}
static __device__ __forceinline__ float bf_hi(unsigned int u) {
  union { unsigned int u; float f; } v; v.u = u & 0xFFFF0000u; return v.f;
}

// ---------- W1 [FIN][HID] f32 -> W1t [HID][FIN] bf16 ----------
__global__ void k_w1t(const float* __restrict__ W1, unsigned short* __restrict__ W1t) {
  int id = blockIdx.x * 256 + threadIdx.x;
  int k = id >> 7;
  int n = id & 127;
  W1t[n * FIN + k] = f2bf(W1[k * HID + n]);
}

// ---------- GEMM1: hb0[NN][HID] = bf16(x @ W1)  (bf16 MFMA, fp32 acc) ----------
#define BM1 64
#define BK1 64
#define BKP1 72
__global__ __launch_bounds__(256) void k_gemm1(const float* __restrict__ x,
                                               const unsigned short* __restrict__ W1t,
                                               unsigned short* __restrict__ hb0) {
  __shared__ unsigned short As[BM1 * BKP1];
  __shared__ unsigned short Bs[HID * BKP1];
  const int t = threadIdx.x;
  const int r0 = blockIdx.x * BM1;
  const int wave = t >> 6, lane = t & 63;
  const int quad = lane >> 4, mr = lane & 15;
  const int mrow0 = (wave & 1) * 32;
  const int ncol0 = (wave >> 1) * 64;

  const int ar = t >> 2, aq = t & 3;
  int grow = r0 + ar; if (grow > NN - 1) grow = NN - 1;
  const float4* xrow = (const float4*)(x + (size_t)grow * FIN);
  const int bn = t >> 1, bh = t & 1;

  const v4f vzero = {0.f, 0.f, 0.f, 0.f};
  v4f acc[2][4];
  #pragma unroll
  for (int mi = 0; mi < 2; ++mi)
    #pragma unroll
    for (int j = 0; j < 4; ++j) acc[mi][j] = vzero;

  for (int k0 = 0; k0 < FIN; k0 += BK1) {
    float4 va[4];
    #pragma unroll
    for (int i = 0; i < 4; ++i) va[i] = xrow[(k0 >> 2) + aq + i * 4];
    us8 vb[4];
    const us8* bp = (const us8*)(W1t + bn * FIN + k0 + bh * 32);
    #pragma unroll
    for (int i = 0; i < 4; ++i) vb[i] = bp[i];

    __syncthreads();
    #pragma unroll
    for (int i = 0; i < 4; ++i) {
      us4 s; s.x = f2bf(va[i].x); s.y = f2bf(va[i].y);
             s.z = f2bf(va[i].z); s.w = f2bf(va[i].w);
      *(us4*)&As[ar * BKP1 + aq * 4 + i * 16] = s;
    }
    #pragma unroll
    for (int i = 0; i < 4; ++i)
      *(us8*)&Bs[bn * BKP1 + bh * 32 + i * 8] = vb[i];
    __syncthreads();

    #pragma unroll
    for (int ks = 0; ks < BK1; ks += 32) {
      v8bf a0 = *(const v8bf*)&As[(mrow0 + mr) * BKP1 + ks + quad * 8];
      v8bf a1 = *(const v8bf*)&As[(mrow0 + 16 + mr) * BKP1 + ks + quad * 8];
      #pragma unroll
      for (int j = 0; j < 4; ++j) {
        v8bf b = *(const v8bf*)&Bs[(ncol0 + j * 16 + mr) * BKP1 + ks + quad * 8];
        acc[0][j] = __builtin_amdgcn_mfma_f32_16x16x32_bf16(a0, b, acc[0][j], 0, 0, 0);
        acc[1][j] = __builtin_amdgcn_mfma_f32_16x16x32_bf16(a1, b, acc[1][j], 0, 0, 0);
      }
    }
  }

  #pragma unroll
  for (int mi = 0; mi < 2; ++mi)
    #pragma unroll
    for (int j = 0; j < 4; ++j)
      #pragma unroll
      for (int rr = 0; rr < 4; ++rr) {
        int row = r0 + mrow0 + mi * 16 + quad * 4 + rr;
        int col = ncol0 + j * 16 + mr;
        if (row < NN) hb0[(size_t)row * HID + col] = f2bf(acc[mi][j][rr]);
      }
}

// ---------- CSR build ----------
__global__ void k_count(const int* __restrict__ dst, int* __restrict__ counts) {
  int e = blockIdx.x * 256 + threadIdx.x;
  if (e < NE) atomicAdd(&counts[dst[e]], 1);
}

// local exclusive scan of 1024 counts per block; per-block total -> bsums
__global__ __launch_bounds__(256) void k_scan_local(const int* __restrict__ counts,
                                                    int* __restrict__ tmp,
                                                    int* __restrict__ bsums) {
  __shared__ int wsum[4];
  const int t = threadIdx.x, lane = t & 63, wid = t >> 6;
  const int base = blockIdx.x * 1024 + t * 4;
  int v[4];
  #pragma unroll
  for (int j = 0; j < 4; ++j) {
    int idx = base + j;
    v[j] = (idx < NN) ? counts[idx] : 0;
  }
  int s = v[0] + v[1] + v[2] + v[3];
  int inc = s;
  #pragma unroll
  for (int off = 1; off < 64; off <<= 1) {
    int u = __shfl_up(inc, off);
    if (lane >= off) inc += u;
  }
  if (lane == 63) wsum[wid] = inc;
  __syncthreads();
  if (t == 0) {
    int a = 0;
    #pragma unroll
    for (int j = 0; j < 4; ++j) { int xv = wsum[j]; wsum[j] = a; a += xv; }
    bsums[blockIdx.x] = a;
  }
  __syncthreads();
  int run = (inc - s) + wsum[wid];
  #pragma unroll
  for (int j = 0; j < 4; ++j) {
    int idx = base + j;
    if (idx < NN) tmp[idx] = run;
    run += v[j];
  }
}

// single-wave scan of the 49 block sums; writes exclusive sums in place + total
__global__ void k_scan_top(int* __restrict__ bsums, int* __restrict__ rowptr) {
  const int lane = threadIdx.x;   // 64 threads
  int v = (lane < NB_SCAN) ? bsums[lane] : 0;
  int inc = v;
  #pragma unroll
  for (int off = 1; off < 64; off <<= 1) {
    int u = __shfl_up(inc, off);
    if (lane >= off) inc += u;
  }
  if (lane < NB_SCAN) bsums[lane] = inc - v;
  if (lane == 63) rowptr[NN] = inc;
}

__global__ __launch_bounds__(256) void k_scan_add(const int* __restrict__ tmp,
                                                  const int* __restrict__ bsums,
                                                  int* __restrict__ rowptr,
                                                  int* __restrict__ nxt) {
  const int t = threadIdx.x;
  const int base = blockIdx.x * 1024 + t * 4;
  const int off = bsums[blockIdx.x];
  #pragma unroll
  for (int j = 0; j < 4; ++j) {
    int idx = base + j;
    if (idx < NN) {
      int val = tmp[idx] + off;
      rowptr[idx] = val;
      nxt[idx] = val;
    }
  }
}

__global__ void k_scatter(const int* __restrict__ src, const int* __restrict__ dst,
                          const float* __restrict__ w, int* __restrict__ nxt,
                          int* __restrict__ csr_src, float* __restrict__ csr_w) {
  int e = blockIdx.x * 256 + threadIdx.x;
  if (e < NE) {
    int i = dst[e];
    int p = atomicAdd(&nxt[i], 1);
    csr_src[p] = src[e];
    csr_w[p]   = w[e];
  }
}

// ---------- SpMM1 (bf16 gather) + bias + relu + dropout -> bf16 ----------
// one wave per row; lane handles cols [2*lane, 2*lane+1] via 4B ushort2 loads
__global__ __launch_bounds__(256) void k_spmm1(const unsigned short* __restrict__ hb0,
                                               const int* __restrict__ rowptr,
                                               const int* __restrict__ csr_src,
                                               const float* __restrict__ csr_w,
                                               const float* __restrict__ b1,
                                               const float* __restrict__ mask,
                                               unsigned short* __restrict__ hb1) {
  const int t = threadIdx.x, lane = t & 63, wv = t >> 6;
  const int i = blockIdx.x * 4 + wv;
  const int c0 = lane * 2;
  const int e0 = rowptr[i], e1 = rowptr[i + 1];
  float a00 = 0.f, a01 = 0.f, a10 = 0.f, a11 = 0.f;
  float a20 = 0.f, a21 = 0.f, a30 = 0.f, a31 = 0.f;
  int e = e0;
  for (; e + 3 < e1; e += 4) {
    int s0 = csr_src[e], s1 = csr_src[e+1], s2 = csr_src[e+2], s3 = csr_src[e+3];
    float w0 = csr_w[e], w1 = csr_w[e+1], w2 = csr_w[e+2], w3 = csr_w[e+3];
    unsigned int u0 = *(const unsigned int*)&hb0[s0 * HID + c0];
    unsigned int u1 = *(const unsigned int*)&hb0[s1 * HID + c0];
    unsigned int u2 = *(const unsigned int*)&hb0[s2 * HID + c0];
    unsigned int u3 = *(const unsigned int*)&hb0[s3 * HID + c0];
    a00 += w0 * bf_lo(u0); a01 += w0 * bf_hi(u0);
    a10 += w1 * bf_lo(u1); a11 += w1 * bf_hi(u1);
    a20 += w2 * bf_lo(u2); a21 += w2 * bf_hi(u2);
    a30 += w3 * bf_lo(u3); a31 += w3 * bf_hi(u3);
  }
  for (; e < e1; ++e) {
    int s = csr_src[e]; float w = csr_w[e];
    unsigned int u = *(const unsigned int*)&hb0[s * HID + c0];
    a00 += w * bf_lo(u); a01 += w * bf_hi(u);
  }
  const float2 bb = *(const float2*)&b1[c0];
  const float2 mk = *(const float2*)&mask[i * HID + c0];
  float v0 = (a00 + a10) + (a20 + a30) + bb.x;
  float v1 = (a01 + a11) + (a21 + a31) + bb.y;
  v0 = fmaxf(v0, 0.f) * mk.x;
  v1 = fmaxf(v1, 0.f) * mk.y;
  unsigned int pk = (unsigned int)f2bf(v0) | ((unsigned int)f2bf(v1) << 16);
  *(unsigned int*)&hb1[i * HID + c0] = pk;
}

// ---------- GEMM2: h2b[NN][40] = bf16(hb1 @ W2) (bf16 MFMA, 48-col padded) ----------
#define BKP2 136
__global__ __launch_bounds__(256) void k_gemm2(const unsigned short* __restrict__ hb1,
                                               const float* __restrict__ W2,
                                               unsigned short* __restrict__ h2b) {
  __shared__ unsigned short As[64 * BKP2];
  __shared__ unsigned short Bs[48 * BKP2];
  const int t = threadIdx.x;
  const int r0 = blockIdx.x * 64;
  const int wave = t >> 6, lane = t & 63;
  const int quad = lane >> 4, mr = lane & 15;
  const int mrow0 = wave * 16;

  const int ar = t >> 2, aq = t & 3;
  int grow = r0 + ar; if (grow > NN - 1) grow = NN - 1;
  const us8* hrow = (const us8*)(hb1 + (size_t)grow * HID);
  #pragma unroll
  for (int i = 0; i < 4; ++i) {
    us8 v = hrow[aq + i * 4];
    *(us8*)&As[ar * BKP2 + aq * 8 + i * 32] = v;
  }
  if (t < 192) {
    int n = t >> 2, q = t & 3;
    #pragma unroll
    for (int kk = 0; kk < 32; ++kk) {
      int k = q * 32 + kk;
      float val = (n < NOUT) ? W2[k * NOUT + n] : 0.f;
      Bs[n * BKP2 + k] = f2bf(val);
    }
  }
  __syncthreads();

  const v4f vzero = {0.f, 0.f, 0.f, 0.f};
  v4f acc[3] = {vzero, vzero, vzero};
  #pragma unroll
  for (int ks = 0; ks < HID; ks += 32) {
    v8bf a = *(const v8bf*)&As[(mrow0 + mr) * BKP2 + ks + quad * 8];
    #pragma unroll
    for (int j = 0; j < 3; ++j) {
      v8bf b = *(const v8bf*)&Bs[(j * 16 + mr) * BKP2 + ks + quad * 8];
      acc[j] = __builtin_amdgcn_mfma_f32_16x16x32_bf16(a, b, acc[j], 0, 0, 0);
    }
  }
  #pragma unroll
  for (int j = 0; j < 3; ++j)
    #pragma unroll
    for (int rr = 0; rr < 4; ++rr) {
      int row = r0 + mrow0 + quad * 4 + rr;
      int col = j * 16 + mr;
      if (row < NN && col < NOUT) h2b[(size_t)row * NOUT + col] = f2bf(acc[j][rr]);
    }
}

// ---------- SpMM2 (bf16 gather) + b2 -> out fp32 ----------
__global__ __launch_bounds__(256) void k_spmm2(const unsigned short* __restrict__ h2b,
                                               const int* __restrict__ rowptr,
                                               const int* __restrict__ csr_src,
                                               const float* __restrict__ csr_w,
                                               const float* __restrict__ b2,
                                               float* __restrict__ out) {
  const int t = threadIdx.x;
  const int lane = t & 63;
  const int i = blockIdx.x * 4 + (t >> 6);
  if (i >= NN) return;
  const int e0 = rowptr[i], e1 = rowptr[i + 1];
  if (lane >= NOUT) return;
  float a0 = 0.f, a1 = 0.f, a2 = 0.f, a3 = 0.f;
  int e = e0;
  for (; e + 3 < e1; e += 4) {
    int s0 = csr_src[e], s1 = csr_src[e+1], s2 = csr_src[e+2], s3 = csr_src[e+3];
    float w0 = csr_w[e], w1 = csr_w[e+1], w2 = csr_w[e+2], w3 = csr_w[e+3];
    a0 += w0 * bf2f(h2b[s0 * NOUT + lane]);
    a1 += w1 * bf2f(h2b[s1 * NOUT + lane]);
    a2 += w2 * bf2f(h2b[s2 * NOUT + lane]);
    a3 += w3 * bf2f(h2b[s3 * NOUT + lane]);
  }
  for (; e < e1; ++e) a0 += csr_w[e] * bf2f(h2b[csr_src[e] * NOUT + lane]);
  out[i * NOUT + lane] = (a0 + a1) + (a2 + a3) + b2[lane];
}

extern "C" void kernel_launch(void* const* d_in, const int* in_sizes, int n_in,
                              void* d_out, int out_size, void* d_ws, size_t ws_size,
                              hipStream_t stream) {
  const float* x   = (const float*)d_in[0];
  const float* W1  = (const float*)d_in[1];
  const float* b1  = (const float*)d_in[2];
  const float* W2  = (const float*)d_in[3];
  const float* b2  = (const float*)d_in[4];
  const float* ew  = (const float*)d_in[5];
  const float* msk = (const float*)d_in[6];
  const int* esrc  = (const int*)d_in[7];
  const int* edst  = (const int*)d_in[8];
  float* out = (float*)d_out;

  char* ws = (char*)d_ws;
  unsigned short* hb0 = (unsigned short*)ws; ws += (size_t)NN * HID * 2;   // 12.8 MB
  unsigned short* hb1 = (unsigned short*)ws; ws += (size_t)NN * HID * 2;   // 12.8 MB
  unsigned short* h2b = (unsigned short*)ws; ws += (size_t)NN * NOUT * 2;  // 4 MB
  unsigned short* W1t = (unsigned short*)ws; ws += (size_t)HID * FIN * 2;  // 128 KB
  int* counts         = (int*)ws;            ws += (size_t)NN * 4;
  int* tmp            = (int*)ws;            ws += (size_t)NN * 4;
  int* rowptr         = (int*)ws;            ws += (size_t)(NN + 16) * 4;
  int* nxt            = (int*)ws;            ws += (size_t)NN * 4;
  int* bsums          = (int*)ws;            ws += (size_t)64 * 4;
  int* csr_src        = (int*)ws;            ws += (size_t)NE * 4;
  float* csr_w        = (float*)ws;          ws += (size_t)NE * 4;

  hipMemsetAsync(counts, 0, (size_t)NN * 4, stream);
  k_w1t       <<<(FIN * HID) / 256, 256, 0, stream>>>(W1, W1t);
  k_gemm1     <<<(NN + BM1 - 1) / BM1, 256, 0, stream>>>(x, W1t, hb0);
  k_count     <<<(NE + 255) / 256, 256, 0, stream>>>(edst, counts);
  k_scan_local<<<NB_SCAN, 256, 0, stream>>>(counts, tmp, bsums);
  k_scan_top  <<<1, 64, 0, stream>>>(bsums, rowptr);
  k_scan_add  <<<NB_SCAN, 256, 0, stream>>>(tmp, bsums, rowptr, nxt);
  k_scatter   <<<(NE + 255) / 256, 256, 0, stream>>>(esrc, edst, ew, nxt, csr_src, csr_w);
  k_spmm1     <<<NN / 4, 256, 0, stream>>>(hb0, rowptr, csr_src, csr_w, b1, msk, hb1);
  k_gemm2     <<<(NN + 63) / 64, 256, 0, stream>>>(hb1, W2, h2b);
  k_spmm2     <<<(NN + 3) / 4, 256, 0, stream>>>(h2b, rowptr, csr_src, csr_w, b2, out);
}